// Round 2
// baseline (460.134 us; speedup 1.0000x reference)
//
#include <hip/hip_runtime.h>

// GraphConvolution (relational GCN, 2 layers, E=4 edge types, self-loop, tanh)
// Key reduction: hidden = (sum_e inv_deg_e ⊙ adj_e) @ h0 + h0  -> build combined A once.
#define BATCH 64
#define NE    4
#define NN    512
#define DIN   64
#define D0    64
#define D1    32

// ---------------------------------------------------------------- K1: h0 = x@W1 + b1
__global__ __launch_bounds__(256) void k_h0(const float* __restrict__ x,
                                            const float* __restrict__ W1,
                                            const float* __restrict__ b1,
                                            float* __restrict__ h0) {
  __shared__ float W1s[DIN][D0];   // 16 KB
  __shared__ float xs[4][DIN];
  int t = threadIdx.x;
  // load W1 (4096 f32) as float4
  #pragma unroll
  for (int i = 0; i < 4; ++i) {
    int idx = t + i * 256;
    reinterpret_cast<float4*>(&W1s[0][0])[idx] = reinterpret_cast<const float4*>(W1)[idx];
  }
  int row0 = blockIdx.x * 4;
  int r = t >> 6, c = t & 63;
  xs[r][c] = x[(size_t)(row0 + r) * DIN + c];
  __syncthreads();
  float acc = b1[c];
  #pragma unroll
  for (int k = 0; k < DIN; ++k) acc += xs[r][k] * W1s[k][c];
  h0[(size_t)(row0 + r) * D0 + c] = acc;
}

// --------------------------------------------- K2: A[b] = sum_e inv_deg ⊙ adj[b,e]
// one wave per (b,n) row; row (4 e-copies) held in registers between reduce+scale.
__global__ __launch_bounds__(256) void k_build_A(const float* __restrict__ adj,
                                                 float* __restrict__ A) {
  int t = threadIdx.x;
  int lane = t & 63;
  int wave = t >> 6;
  int idx = blockIdx.x * 4 + wave;                   // [0, B*N)
  const size_t estride = (size_t)NN * NN;            // 262144
  const float* base = adj + (size_t)(idx >> 9) * NE * estride + (size_t)(idx & 511) * NN;
  float4 v[NE][2];
  float inv[NE];
  #pragma unroll
  for (int e = 0; e < NE; ++e) {
    const float4* p = reinterpret_cast<const float4*>(base + e * estride);
    v[e][0] = p[lane];
    v[e][1] = p[lane + 64];
    float s = v[e][0].x + v[e][0].y + v[e][0].z + v[e][0].w
            + v[e][1].x + v[e][1].y + v[e][1].z + v[e][1].w;
    #pragma unroll
    for (int off = 32; off; off >>= 1) s += __shfl_xor(s, off);
    inv[e] = 1.0f / (s + 1.0f);
  }
  float4 vo[2];
  float* po = reinterpret_cast<float*>(vo);
  #pragma unroll
  for (int j = 0; j < 8; ++j) po[j] = 0.0f;
  #pragma unroll
  for (int e = 0; e < NE; ++e) {
    const float* pv = reinterpret_cast<const float*>(&v[e][0]);
    #pragma unroll
    for (int j = 0; j < 8; ++j) po[j] += inv[e] * pv[j];
  }
  float4* out = reinterpret_cast<float4*>(A + (size_t)idx * NN);
  out[lane]      = vo[0];
  out[lane + 64] = vo[1];
}

// --------------- K3: o0 = tanh(A@h0 + h0) @ W2 + b2   (hidden kept in LDS only)
// per block: 64 rows x 64 cols of one batch; thread tile 4x4; K chunks of 32.
__global__ __launch_bounds__(256) void k_layer1(const float* __restrict__ A,
                                                const float* __restrict__ h0,
                                                const float* __restrict__ W2,
                                                const float* __restrict__ b2,
                                                float* __restrict__ o0) {
  __shared__ float As[32][68];     // A chunk, transposed [k][row], pad 4 for b128 align
  __shared__ float Bs[32][D0];     // h0 chunk [k][col]
  __shared__ float Hs[64][D0];     // hidden tile (post-tanh)
  __shared__ float W2s[D0][D1];
  int t = threadIdx.x;
  int bb = blockIdx.x >> 3;
  int rt = blockIdx.x & 7;
  int brow = rt * 64;
  // preload W2 (2048 f32)
  {
    reinterpret_cast<float4*>(&W2s[0][0])[t]       = reinterpret_cast<const float4*>(W2)[t];
    reinterpret_cast<float4*>(&W2s[0][0])[t + 256] = reinterpret_cast<const float4*>(W2)[t + 256];
  }
  int tx = t & 15, ty = t >> 4;
  float acc[4][4] = {};
  const float* Ab = A  + ((size_t)bb * NN + brow) * NN;
  const float* Hb = h0 + (size_t)bb * NN * D0;
  int lrow = t >> 2, lkq = t & 3;   // A staging: row 0..63, k quad 0..3
  int bk = t >> 3, bcq = t & 7;     // B staging: k 0..31, col quad 0..7

  for (int kt = 0; kt < 16; ++kt) {
    int k0 = kt * 32;
    float4 a0 = *reinterpret_cast<const float4*>(Ab + (size_t)lrow * NN + k0 + lkq * 4);
    float4 a1 = *reinterpret_cast<const float4*>(Ab + (size_t)lrow * NN + k0 + 16 + lkq * 4);
    float4 b0 = *reinterpret_cast<const float4*>(Hb + (size_t)(k0 + bk) * D0 + bcq * 4);
    float4 b1v = *reinterpret_cast<const float4*>(Hb + (size_t)(k0 + bk) * D0 + 32 + bcq * 4);
    __syncthreads();                       // previous compute done
    {
      const float* pa0 = reinterpret_cast<const float*>(&a0);
      const float* pa1 = reinterpret_cast<const float*>(&a1);
      #pragma unroll
      for (int j = 0; j < 4; ++j) {
        As[lkq * 4 + j][lrow]      = pa0[j];
        As[16 + lkq * 4 + j][lrow] = pa1[j];
      }
      *reinterpret_cast<float4*>(&Bs[bk][bcq * 4])      = b0;
      *reinterpret_cast<float4*>(&Bs[bk][32 + bcq * 4]) = b1v;
    }
    __syncthreads();
    #pragma unroll
    for (int k = 0; k < 32; ++k) {
      float4 av = *reinterpret_cast<const float4*>(&As[k][ty * 4]);
      float4 bv = *reinterpret_cast<const float4*>(&Bs[k][tx * 4]);
      float a_[4] = {av.x, av.y, av.z, av.w};
      float b_[4] = {bv.x, bv.y, bv.z, bv.w};
      #pragma unroll
      for (int i = 0; i < 4; ++i)
        #pragma unroll
        for (int j = 0; j < 4; ++j) acc[i][j] += a_[i] * b_[j];
    }
  }
  __syncthreads();
  // hidden tile -> LDS with tanh + self-loop
  #pragma unroll
  for (int i = 0; i < 4; ++i) {
    int row = ty * 4 + i;
    float4 hv = *reinterpret_cast<const float4*>(Hb + (size_t)(brow + row) * D0 + tx * 4);
    Hs[row][tx * 4 + 0] = tanhf(acc[i][0] + hv.x);
    Hs[row][tx * 4 + 1] = tanhf(acc[i][1] + hv.y);
    Hs[row][tx * 4 + 2] = tanhf(acc[i][2] + hv.z);
    Hs[row][tx * 4 + 3] = tanhf(acc[i][3] + hv.w);
  }
  __syncthreads();
  // o0 = Hs @ W2 + b2
  int col = t & 31, r0 = (t >> 5) * 8;
  float bias = b2[col];
  for (int r = r0; r < r0 + 8; ++r) {
    float s = bias;
    #pragma unroll
    for (int k = 0; k < D0; ++k) s += Hs[r][k] * W2s[k][col];
    o0[((size_t)bb * NN + brow + r) * D1 + col] = s;
  }
}

// ---------------------------- K4: out = tanh(A@o0 + o0)   (thread tile 4x2)
__global__ __launch_bounds__(256) void k_layer2(const float* __restrict__ A,
                                                const float* __restrict__ o0,
                                                float* __restrict__ out) {
  __shared__ float As[32][68];
  __shared__ float Bs[32][D1];
  int t = threadIdx.x;
  int bb = blockIdx.x >> 3, rt = blockIdx.x & 7, brow = rt * 64;
  int tx = t & 15, ty = t >> 4;
  float acc[4][2] = {};
  const float* Ab = A  + ((size_t)bb * NN + brow) * NN;
  const float* Ob = o0 + (size_t)bb * NN * D1;
  int lrow = t >> 2, lkq = t & 3;
  int bk = t >> 3, bcq = t & 7;

  for (int kt = 0; kt < 16; ++kt) {
    int k0 = kt * 32;
    float4 a0 = *reinterpret_cast<const float4*>(Ab + (size_t)lrow * NN + k0 + lkq * 4);
    float4 a1 = *reinterpret_cast<const float4*>(Ab + (size_t)lrow * NN + k0 + 16 + lkq * 4);
    float4 bv = *reinterpret_cast<const float4*>(Ob + (size_t)(k0 + bk) * D1 + bcq * 4);
    __syncthreads();
    {
      const float* pa0 = reinterpret_cast<const float*>(&a0);
      const float* pa1 = reinterpret_cast<const float*>(&a1);
      #pragma unroll
      for (int j = 0; j < 4; ++j) {
        As[lkq * 4 + j][lrow]      = pa0[j];
        As[16 + lkq * 4 + j][lrow] = pa1[j];
      }
      *reinterpret_cast<float4*>(&Bs[bk][bcq * 4]) = bv;
    }
    __syncthreads();
    #pragma unroll
    for (int k = 0; k < 32; ++k) {
      float4 av = *reinterpret_cast<const float4*>(&As[k][ty * 4]);
      float2 b2v = *reinterpret_cast<const float2*>(&Bs[k][tx * 2]);
      float a_[4] = {av.x, av.y, av.z, av.w};
      #pragma unroll
      for (int i = 0; i < 4; ++i) {
        acc[i][0] += a_[i] * b2v.x;
        acc[i][1] += a_[i] * b2v.y;
      }
    }
  }
  #pragma unroll
  for (int i = 0; i < 4; ++i) {
    int row = brow + ty * 4 + i;
    float2 self = *reinterpret_cast<const float2*>(Ob + (size_t)row * D1 + tx * 2);
    float2 r;
    r.x = tanhf(acc[i][0] + self.x);
    r.y = tanhf(acc[i][1] + self.y);
    *reinterpret_cast<float2*>(out + ((size_t)bb * NN + row) * D1 + tx * 2) = r;
  }
}

extern "C" void kernel_launch(void* const* d_in, const int* in_sizes, int n_in,
                              void* d_out, int out_size, void* d_ws, size_t ws_size,
                              hipStream_t stream) {
  const float* x   = (const float*)d_in[0];
  const float* adj = (const float*)d_in[1];
  const float* W1  = (const float*)d_in[2];
  const float* b1  = (const float*)d_in[3];
  const float* W2  = (const float*)d_in[4];
  const float* b2  = (const float*)d_in[5];
  float* out = (float*)d_out;

  char* ws = (char*)d_ws;
  float* A  = (float*)ws;                                    // 64*512*512*4 = 67108864 B
  float* h0 = (float*)(ws + (size_t)67108864);               // 8388608 B
  float* o0 = (float*)(ws + (size_t)67108864 + 8388608);     // 4194304 B

  k_h0     <<<BATCH * NN / 4, 256, 0, stream>>>(x, W1, b1, h0);
  k_build_A<<<BATCH * NN / 4, 256, 0, stream>>>(adj, A);
  k_layer1 <<<BATCH * 8,      256, 0, stream>>>(A, h0, W2, b2, o0);
  k_layer2 <<<BATCH * 8,      256, 0, stream>>>(A, o0, out);
}

// Round 5
// 409.896 us; speedup vs baseline: 1.1226x; 1.1226x over previous
//
#include <hip/hip_runtime.h>

// Relational GCN fwd: hidden = tanh((Σe inv_deg⊙adj_e)@h0 + h0); out = tanh(A@(hidden@W2+b2) + o0)
// A is built once (bf16), both layer GEMMs use mfma_f32_16x16x32_bf16; self-loops stay f32.
#define BATCH 64
#define NE    4
#define NN    512

typedef __attribute__((ext_vector_type(4))) float f32x4;
typedef __attribute__((ext_vector_type(8))) short s16x8;
typedef __attribute__((ext_vector_type(8))) unsigned short u16x8;

__device__ __forceinline__ unsigned short f2bf(float f) {
  unsigned u = __builtin_bit_cast(unsigned, f);
  u += 0x7fffu + ((u >> 16) & 1u);     // RNE (inputs are finite)
  return (unsigned short)(u >> 16);
}

// ---------------- K1: h0 = x@W1 + b1 -> h0 f32 [B][512][64], h0T bf16 [B][64][512]
__global__ __launch_bounds__(256) void k_h0(const float* __restrict__ x,
                                            const float* __restrict__ W1,
                                            const float* __restrict__ b1,
                                            float* __restrict__ h0,
                                            unsigned short* __restrict__ h0T) {
  __shared__ float W1s[64][68];
  __shared__ float xs[64][68];
  __shared__ float Ts[64][68];
  int t = threadIdx.x;
  int b = blockIdx.x >> 3;
  int mt = (blockIdx.x & 7) * 64;
  #pragma unroll
  for (int i = 0; i < 4; ++i) {                 // W1: 1024 float4
    int idx = i * 256 + t;
    int k = idx >> 4, cq = idx & 15;
    *reinterpret_cast<float4*>(&W1s[k][cq * 4]) = reinterpret_cast<const float4*>(W1)[idx];
  }
  const float* xb = x + ((size_t)b * NN + mt) * 64;
  #pragma unroll
  for (int i = 0; i < 4; ++i) {                 // x tile: 1024 float4
    int idx = i * 256 + t;
    int m = idx >> 4, cq = idx & 15;
    *reinterpret_cast<float4*>(&xs[m][cq * 4]) = reinterpret_cast<const float4*>(xb)[idx];
  }
  __syncthreads();
  int c = t & 63, rg = t >> 6;
  float acc[16];
  float bias = b1[c];
  #pragma unroll
  for (int i = 0; i < 16; ++i) acc[i] = bias;
  for (int k = 0; k < 64; ++k) {
    float w = W1s[k][c];
    #pragma unroll
    for (int i = 0; i < 16; ++i) acc[i] += xs[rg * 16 + i][k] * w;
  }
  float* h0b = h0 + ((size_t)b * NN + mt) * 64;
  #pragma unroll
  for (int i = 0; i < 16; ++i) {
    h0b[(size_t)(rg * 16 + i) * 64 + c] = acc[i];
    Ts[c][rg * 16 + i] = acc[i];                // transpose via LDS
  }
  __syncthreads();
  int d = t >> 2, mq = t & 3;
  unsigned short* dst = h0T + ((size_t)b * 64 + d) * NN + mt + mq * 16;
  u16x8 oa, ob;
  #pragma unroll
  for (int j = 0; j < 8; ++j) oa[j] = f2bf(Ts[d][mq * 16 + j]);
  #pragma unroll
  for (int j = 0; j < 8; ++j) ob[j] = f2bf(Ts[d][mq * 16 + 8 + j]);
  *reinterpret_cast<u16x8*>(dst) = oa;
  *reinterpret_cast<u16x8*>(dst + 8) = ob;
}

// ---------------- K2: A[b] = Σe inv_deg ⊙ adj[b,e]  (bf16 out; one wave per row)
__global__ __launch_bounds__(256) void k_build_A(const float* __restrict__ adj,
                                                 unsigned short* __restrict__ A) {
  int t = threadIdx.x;
  int lane = t & 63;
  int wave = t >> 6;
  int idx = blockIdx.x * 4 + wave;                      // [0, B*N)
  const size_t estride = (size_t)NN * NN;
  const float* base = adj + (size_t)(idx >> 9) * NE * estride + (size_t)(idx & 511) * NN;
  float4 v[NE][2];
  float inv[NE];
  #pragma unroll
  for (int e = 0; e < NE; ++e) {
    const float4* p = reinterpret_cast<const float4*>(base + e * estride);
    v[e][0] = p[lane * 2];                               // m = lane*8 .. lane*8+7 (contig)
    v[e][1] = p[lane * 2 + 1];
    float s = v[e][0].x + v[e][0].y + v[e][0].z + v[e][0].w
            + v[e][1].x + v[e][1].y + v[e][1].z + v[e][1].w;
    #pragma unroll
    for (int off = 32; off; off >>= 1) s += __shfl_xor(s, off);
    inv[e] = 1.0f / (s + 1.0f);
  }
  float po[8] = {0, 0, 0, 0, 0, 0, 0, 0};
  #pragma unroll
  for (int e = 0; e < NE; ++e) {
    const float* pv = reinterpret_cast<const float*>(&v[e][0]);
    #pragma unroll
    for (int j = 0; j < 8; ++j) po[j] += inv[e] * pv[j];
  }
  u16x8 ob;
  #pragma unroll
  for (int j = 0; j < 8; ++j) ob[j] = f2bf(po[j]);
  *reinterpret_cast<u16x8*>(A + (size_t)idx * NN + lane * 8) = ob;
}

// ---------------- K3: o0 = tanh(A@h0 + h0) @ W2 + b2 ; writes o0 f32 + o0T bf16
__global__ __launch_bounds__(256) void k_layer1(const unsigned short* __restrict__ A,
                                                const unsigned short* __restrict__ h0T,
                                                const float* __restrict__ h0,
                                                const float* __restrict__ W2,
                                                const float* __restrict__ b2,
                                                float* __restrict__ o0,
                                                unsigned short* __restrict__ o0T) {
  __shared__ unsigned short LT[64][520];   // h0T tile [d][m], pad->bank-uniform b128
  __shared__ unsigned short Hs[64][72];    // hidden bf16 (144B rows, 16B aligned)
  __shared__ unsigned short W2T[32][72];
  int t = threadIdx.x;
  int b = blockIdx.x >> 3;
  int brow = (blockIdx.x & 7) * 64;
  const u16x8* src = reinterpret_cast<const u16x8*>(h0T + (size_t)b * 64 * NN);
  #pragma unroll
  for (int i = 0; i < 16; ++i) {           // 4096 16B chunks
    int idx = i * 256 + t;
    int d = idx >> 6, ch = idx & 63;
    *reinterpret_cast<u16x8*>(&LT[d][ch * 8]) = src[idx];
  }
  {
    int d0 = t >> 2, d1b = (t & 3) * 8;
    #pragma unroll
    for (int j = 0; j < 8; ++j)
      W2T[d1b + j][d0] = f2bf(W2[(size_t)d0 * 32 + d1b + j]);
  }
  __syncthreads();
  int lane = t & 63, w = t >> 6;
  int cl = lane & 15, g = lane >> 4;
  int wrow = w * 16;
  const unsigned short* Ab = A + ((size_t)b * NN + brow + wrow + cl) * NN;
  f32x4 acc[4] = {};
  for (int ks = 0; ks < 16; ++ks) {
    s16x8 af = *reinterpret_cast<const s16x8*>(Ab + ks * 32 + g * 8);
    #pragma unroll
    for (int n = 0; n < 4; ++n) {
      s16x8 bf = *reinterpret_cast<const s16x8*>(&LT[n * 16 + cl][ks * 32 + g * 8]);
      acc[n] = __builtin_amdgcn_mfma_f32_16x16x32_bf16(af, bf, acc[n], 0, 0, 0);
    }
  }
  // epilogue1: tanh(acc + h0 f32) -> Hs bf16  (C/D map: col=lane&15, row=g*4+reg)
  const float* h0r = h0 + ((size_t)b * NN + brow + wrow) * 64;
  #pragma unroll
  for (int n = 0; n < 4; ++n) {
    #pragma unroll
    for (int q = 0; q < 4; ++q) {
      int row = g * 4 + q;
      float hv = h0r[(size_t)row * 64 + n * 16 + cl];
      Hs[wrow + row][n * 16 + cl] = f2bf(tanhf(acc[n][q] + hv));
    }
  }
  __syncthreads();
  // GEMM2: o0 = Hs @ W2 (K=64)
  f32x4 acc2[2] = {};
  #pragma unroll
  for (int ks = 0; ks < 2; ++ks) {
    s16x8 hf = *reinterpret_cast<const s16x8*>(&Hs[wrow + cl][ks * 32 + g * 8]);
    #pragma unroll
    for (int n = 0; n < 2; ++n) {
      s16x8 wf = *reinterpret_cast<const s16x8*>(&W2T[n * 16 + cl][ks * 32 + g * 8]);
      acc2[n] = __builtin_amdgcn_mfma_f32_16x16x32_bf16(hf, wf, acc2[n], 0, 0, 0);
    }
  }
  float* o0r = o0 + ((size_t)b * NN + brow + wrow) * 32;
  unsigned short* oTb = o0T + (size_t)b * 32 * NN + (brow + wrow);
  #pragma unroll
  for (int n = 0; n < 2; ++n) {
    float bias = b2[n * 16 + cl];
    #pragma unroll
    for (int q = 0; q < 4; ++q) {
      int row = g * 4 + q;
      float val = acc2[n][q] + bias;
      o0r[(size_t)row * 32 + n * 16 + cl] = val;
      oTb[(size_t)(n * 16 + cl) * NN + row] = f2bf(val);   // scattered 2B; L2 merges
    }
  }
}

// ---------------- K4: out = tanh(A@o0 + o0)
__global__ __launch_bounds__(256) void k_layer2(const unsigned short* __restrict__ A,
                                                const unsigned short* __restrict__ o0T,
                                                const float* __restrict__ o0,
                                                float* __restrict__ out) {
  __shared__ unsigned short OT[32][520];
  int t = threadIdx.x;
  int b = blockIdx.x >> 3;
  int brow = (blockIdx.x & 7) * 64;
  const u16x8* src = reinterpret_cast<const u16x8*>(o0T + (size_t)b * 32 * NN);
  #pragma unroll
  for (int i = 0; i < 8; ++i) {            // 2048 16B chunks
    int idx = i * 256 + t;
    int d = idx >> 6, ch = idx & 63;
    *reinterpret_cast<u16x8*>(&OT[d][ch * 8]) = src[idx];
  }
  __syncthreads();
  int lane = t & 63, w = t >> 6;
  int cl = lane & 15, g = lane >> 4;
  int wrow = w * 16;
  const unsigned short* Ab = A + ((size_t)b * NN + brow + wrow + cl) * NN;
  f32x4 acc[2] = {};
  for (int ks = 0; ks < 16; ++ks) {
    s16x8 af = *reinterpret_cast<const s16x8*>(Ab + ks * 32 + g * 8);
    #pragma unroll
    for (int n = 0; n < 2; ++n) {
      s16x8 bf = *reinterpret_cast<const s16x8*>(&OT[n * 16 + cl][ks * 32 + g * 8]);
      acc[n] = __builtin_amdgcn_mfma_f32_16x16x32_bf16(af, bf, acc[n], 0, 0, 0);
    }
  }
  const float* o0r = o0 + ((size_t)b * NN + brow + wrow) * 32;
  float* outr = out + ((size_t)b * NN + brow + wrow) * 32;
  #pragma unroll
  for (int n = 0; n < 2; ++n) {
    #pragma unroll
    for (int q = 0; q < 4; ++q) {
      int row = g * 4 + q;
      float self = o0r[(size_t)row * 32 + n * 16 + cl];
      outr[(size_t)row * 32 + n * 16 + cl] = tanhf(acc[n][q] + self);
    }
  }
}

extern "C" void kernel_launch(void* const* d_in, const int* in_sizes, int n_in,
                              void* d_out, int out_size, void* d_ws, size_t ws_size,
                              hipStream_t stream) {
  const float* x   = (const float*)d_in[0];
  const float* adj = (const float*)d_in[1];
  const float* W1  = (const float*)d_in[2];
  const float* b1  = (const float*)d_in[3];
  const float* W2  = (const float*)d_in[4];
  const float* b2  = (const float*)d_in[5];
  float* out = (float*)d_out;

  char* ws = (char*)d_ws;
  unsigned short* A   = (unsigned short*)ws;                          // 33,554,432 B
  float*          h0  = (float*)(ws + 33554432);                      //  8,388,608 B
  unsigned short* h0T = (unsigned short*)(ws + 33554432 + 8388608);   //  4,194,304 B
  float*          o0  = (float*)(ws + 46137344);                      //  4,194,304 B
  unsigned short* o0T = (unsigned short*)(ws + 50331648);             //  2,097,152 B

  k_h0     <<<BATCH * 8,      256, 0, stream>>>(x, W1, b1, h0, h0T);
  k_build_A<<<BATCH * NN / 4, 256, 0, stream>>>(adj, A);
  k_layer1 <<<BATCH * 8,      256, 0, stream>>>(A, h0T, h0, W2, b2, o0, o0T);
  k_layer2 <<<BATCH * 8,      256, 0, stream>>>(A, o0T, o0, out);
}